// Round 1
// baseline (4976.532 us; speedup 1.0000x reference)
//
#include <hip/hip_runtime.h>
#include <math.h>

// Layout: activations kept as (B, L, C) row-major, C contiguous. B=16, L=600, C=256.
#define NROWS 9600   // B*L
#define EPSv 1e-5f

// ---------------- gamma/beta for all 32 CCBNs ----------------
__global__ void k_gamma_beta(const float* __restrict__ spk, const float* __restrict__ noise,
                             const float* __restrict__ g_w, const float* __restrict__ g_b,
                             const float* __restrict__ b_w, const float* __restrict__ b_b,
                             const float* __restrict__ tl_g_w, const float* __restrict__ tl_g_b,
                             const float* __restrict__ tl_b_w, const float* __restrict__ tl_b_b,
                             float* __restrict__ gammas, float* __restrict__ betas) {
  int i = blockIdx.x >> 4;   // ccbn index 0..31
  int b = blockIdx.x & 15;
  int c = threadIdx.x;
  const float *gw, *bw, *gbias, *bbias;
  if (i < 30) { gw = g_w + (size_t)i*65536; bw = b_w + (size_t)i*65536; gbias = g_b + i*256; bbias = b_b + i*256; }
  else { int j = i - 30; gw = tl_g_w + (size_t)j*65536; bw = tl_b_w + (size_t)j*65536; gbias = tl_g_b + j*256; bbias = tl_b_b + j*256; }
  float g = 0.f, bt = 0.f;
  for (int k = 0; k < 256; ++k) {
    float cv = (k < 128) ? spk[b*128 + k] : noise[b*128 + k - 128];
    g  += cv * gw[k*256 + c];
    bt += cv * bw[k*256 + c];
  }
  gammas[i*4096 + b*256 + c] = 1.0f + g + gbias[c];
  betas [i*4096 + b*256 + c] = bt + bbias[c];
}

// ---------------- embedding gather ----------------
__global__ void k_embed(const int* __restrict__ inp, const float* __restrict__ emb,
                        float* __restrict__ x) {
  int r = blockIdx.x;        // 0..9599
  int c = threadIdx.x;
  int row = inp[r];
  x[(size_t)r*256 + c] = emb[(size_t)row*256 + c];
}

// ---------------- CCBN stats (two-pass) ----------------
__global__ void k_stats1(const float* __restrict__ in, float* __restrict__ part) {
  int blk = blockIdx.x; int c = threadIdx.x;   // 192 blocks x 50 rows
  float s = 0.f, s2 = 0.f;
  int r0 = blk * 50;
  for (int r = r0; r < r0 + 50; ++r) {
    float v = in[(size_t)r*256 + c];
    s += v; s2 += v*v;
  }
  part[blk*512 + c] = s;
  part[blk*512 + 256 + c] = s2;
}
__global__ void k_stats2(const float* __restrict__ part, float* __restrict__ musr) {
  int c = threadIdx.x;
  float s = 0.f, s2 = 0.f;
  for (int g = 0; g < 192; ++g) { s += part[g*512 + c]; s2 += part[g*512 + 256 + c]; }
  float mu = s * (1.0f/9600.0f);
  float var = s2 * (1.0f/9600.0f) - mu*mu;
  musr[c] = mu;
  musr[256 + c] = rsqrtf(var + EPSv);
}

// ---------------- normalize + affine + relu ----------------
__global__ void k_normrelu(const float* __restrict__ in, float* __restrict__ out,
                           const float* __restrict__ musr,
                           const float* __restrict__ gamma, const float* __restrict__ beta) {
  int r = blockIdx.x; int c = threadIdx.x;
  int b = r / 600;
  float v = (in[(size_t)r*256 + c] - musr[c]) * musr[256 + c] * gamma[b*256 + c] + beta[b*256 + c];
  out[(size_t)r*256 + c] = fmaxf(v, 0.f);
}

// ---------------- dilated conv as tiled GEMM ----------------
// out tile: 64 l x 64 co per block. mode 0: write (+bias); mode 1: out += result (+bias).
template<int K>
__global__ __launch_bounds__(256) void k_conv(const float* __restrict__ zin, float* __restrict__ out,
                       const float* __restrict__ w, const float* __restrict__ bias,
                       int dil, int mode) {
  __shared__ float Zt[80*20];        // rows padded to 20 floats (bank-conflict break)
  __shared__ float Wt[16*K*64];
  int t = threadIdx.x;
  int b  = blockIdx.x / 10;
  int l0 = (blockIdx.x % 10) * 64;
  int co0 = blockIdx.y * 64;
  int PAD = ((K-1)/2) * dil;
  int ROWS = 64 + 2*PAD;
  int rt = t >> 4, ct = t & 15;
  float acc[4][4] = {{0.f}};
  const float* zb = zin + (size_t)b*600*256;

  for (int ci0 = 0; ci0 < 256; ci0 += 16) {
    __syncthreads();
    // stage Z rows [l0-PAD, l0+63+PAD] x 16 ci, zero-padded
    for (int idx = t; idx < ROWS*16; idx += 256) {
      int row = idx >> 4, j = idx & 15;
      int gl = l0 + row - PAD;
      float v = 0.f;
      if (gl >= 0 && gl < 600) v = zb[(size_t)gl*256 + ci0 + j];
      Zt[row*20 + j] = v;
    }
    // stage W: dense 16*K-float runs per co, split across 4 threads
    {
      int coi = t >> 2, q = t & 3;
      const float* wsrc = w + ((size_t)(co0 + coi) * 256 + ci0) * K + q * 4 * K;
      #pragma unroll
      for (int m4 = 0; m4 < K; ++m4) {
        float4 v = *(const float4*)(wsrc + m4*4);
        float vv[4] = {v.x, v.y, v.z, v.w};
        #pragma unroll
        for (int comp = 0; comp < 4; ++comp) {
          int e = q*4*K + m4*4 + comp;
          int j = e / K, k = e % K;
          Wt[(j*K + k)*64 + coi] = vv[comp];
        }
      }
    }
    __syncthreads();
    // compute
    for (int k = 0; k < K; ++k) {
      int rbase = k * dil;
      #pragma unroll
      for (int jj = 0; jj < 16; jj += 4) {
        float4 zv[4]; float4 wv[4];
        #pragma unroll
        for (int i = 0; i < 4; ++i)
          zv[i] = *(const float4*)&Zt[(rt*4 + i + rbase)*20 + jj];
        #pragma unroll
        for (int q = 0; q < 4; ++q)
          wv[q] = *(const float4*)&Wt[((jj + q)*K + k)*64 + ct*4];
        #pragma unroll
        for (int i = 0; i < 4; ++i) {
          const float* zi = (const float*)&zv[i];
          #pragma unroll
          for (int q = 0; q < 4; ++q) {
            float zq = zi[q];
            acc[i][0] += zq * wv[q].x;
            acc[i][1] += zq * wv[q].y;
            acc[i][2] += zq * wv[q].z;
            acc[i][3] += zq * wv[q].w;
          }
        }
      }
    }
  }
  // epilogue
  float4 bi = *(const float4*)&bias[co0 + ct*4];
  #pragma unroll
  for (int i = 0; i < 4; ++i) {
    int l = l0 + rt*4 + i;
    if (l < 600) {
      float4 v;
      v.x = acc[i][0] + bi.x; v.y = acc[i][1] + bi.y;
      v.z = acc[i][2] + bi.z; v.w = acc[i][3] + bi.w;
      float4* dst = (float4*)&out[((size_t)(b*600 + l))*256 + co0 + ct*4];
      if (mode) { float4 o = *dst; v.x += o.x; v.y += o.y; v.z += o.z; v.w += o.w; }
      *dst = v;
    }
  }
}

// ---------------- token-length final 256->1 conv + relu ----------------
__global__ void k_tl2(const float* __restrict__ z, const float* __restrict__ w2,
                      const float* __restrict__ b2, float* __restrict__ tl) {
  int t = threadIdx.x;
  int row = blockIdx.x * 4 + (t >> 6);
  int lane = t & 63;
  float4 zr = *(const float4*)&z[(size_t)row*256 + lane*4];
  float4 wr = *(const float4*)&w2[lane*4];
  float s = zr.x*wr.x + zr.y*wr.y + zr.z*wr.z + zr.w*wr.w;
  for (int m = 32; m >= 1; m >>= 1) s += __shfl_xor(s, m, 64);
  if (lane == 0) tl[row] = fmaxf(s + b2[0], 0.f);
}

// ---------------- per-batch cumsum -> ends (output 1) + centers ----------------
__global__ void k_cumsum(const float* __restrict__ tl, float* __restrict__ centers,
                         float* __restrict__ out_len) {
  int b = blockIdx.x; int lane = threadIdx.x;  // 64 threads
  float carry = 0.f;
  for (int ch = 0; ch < 10; ++ch) {
    int l = ch*64 + lane;
    float v = (l < 600) ? tl[b*600 + l] : 0.f;
    float s = v;
    #pragma unroll
    for (int off = 1; off < 64; off <<= 1) {
      float n = __shfl_up(s, off, 64);
      if (lane >= off) s += n;
    }
    float ends = carry + s;
    if (l < 600) {
      centers[b*600 + l] = ends - 0.5f*v;
      out_len[b*600 + l] = ends;
    }
    carry = __shfl(ends, 63, 64);
  }
}

// ---------------- fused softmax-alignment einsum ----------------
// block = (b, 24 consecutive out positions). p[o][l] softmax weights in LDS.
__global__ __launch_bounds__(256) void k_align(const float* __restrict__ feats,
                        const float* __restrict__ centers, float* __restrict__ outp) {
  __shared__ float cen[600];
  __shared__ float p[24*604];
  __shared__ float ssum[24];
  int b = blockIdx.y;
  int o0 = blockIdx.x * 24;
  int t = threadIdx.x;
  for (int i = t; i < 600; i += 256) cen[i] = centers[b*600 + i];
  __syncthreads();
  int wv = t >> 6, lane = t & 63;
  for (int s = 0; s < 6; ++s) {
    int oi = wv*6 + s;
    float opos = (float)(o0 + oi);
    float m = -1e30f;
    for (int l = lane; l < 600; l += 64) {
      float d = cen[l] - opos;
      m = fmaxf(m, -d*d*0.1f);
    }
    #pragma unroll
    for (int mm = 32; mm >= 1; mm >>= 1) m = fmaxf(m, __shfl_xor(m, mm, 64));
    float sum = 0.f;
    for (int l = lane; l < 600; l += 64) {
      float d = cen[l] - opos;
      float e = __expf(-d*d*0.1f - m);
      p[oi*604 + l] = e;
      sum += e;
    }
    #pragma unroll
    for (int mm = 32; mm >= 1; mm >>= 1) sum += __shfl_xor(sum, mm, 64);
    if (lane == 0) ssum[oi] = sum;
  }
  __syncthreads();
  int c = t;
  float acc[24];
  #pragma unroll
  for (int i = 0; i < 24; ++i) acc[i] = 0.f;
  const float* fb = feats + (size_t)b*600*256 + c;
  for (int ll = 0; ll < 600; ll += 4) {
    float f0 = fb[(size_t)(ll+0)*256];
    float f1 = fb[(size_t)(ll+1)*256];
    float f2 = fb[(size_t)(ll+2)*256];
    float f3 = fb[(size_t)(ll+3)*256];
    #pragma unroll
    for (int oi = 0; oi < 24; ++oi) {
      float4 pv = *(const float4*)&p[oi*604 + ll];
      acc[oi] += pv.x*f0 + pv.y*f1 + pv.z*f2 + pv.w*f3;
    }
  }
  #pragma unroll
  for (int oi = 0; oi < 24; ++oi) {
    float inv = 1.0f / ssum[oi];
    outp[((size_t)b*6000 + o0 + oi)*256 + c] = acc[oi] * inv;
  }
}

extern "C" void kernel_launch(void* const* d_in, const int* in_sizes, int n_in,
                              void* d_out, int out_size, void* d_ws, size_t ws_size,
                              hipStream_t stream) {
  const int*   inputs = (const int*)  d_in[0];
  const float* spk    = (const float*)d_in[1];
  const float* noise  = (const float*)d_in[2];
  const float* emb    = (const float*)d_in[3];
  const float* conv_w = (const float*)d_in[4];
  const float* conv_b = (const float*)d_in[5];
  const float* g_w    = (const float*)d_in[6];
  const float* g_b    = (const float*)d_in[7];
  const float* b_w    = (const float*)d_in[8];
  const float* b_b    = (const float*)d_in[9];
  const float* tl_g_w = (const float*)d_in[10];
  const float* tl_g_b = (const float*)d_in[11];
  const float* tl_b_w = (const float*)d_in[12];
  const float* tl_b_b = (const float*)d_in[13];
  const float* tl_c1_w = (const float*)d_in[14];
  const float* tl_c1_b = (const float*)d_in[15];
  const float* tl_c2_w = (const float*)d_in[16];
  const float* tl_c2_b = (const float*)d_in[17];
  float* out = (float*)d_out;

  float* ws = (float*)d_ws;
  float* x      = ws;                 // 2457600 floats (residual stream / unaligned feats)
  float* A      = x + 2457600;        // conv out buffer
  float* Bf     = A + 2457600;        // normalized+relu buffer
  float* gammas = Bf + 2457600;       // 32*16*256
  float* betas  = gammas + 131072;
  float* part   = betas + 131072;     // 192*512
  float* musr   = part + 98304;       // 512
  float* tl     = musr + 512;         // 9600
  float* cen    = tl + 9600;          // 9600

  k_gamma_beta<<<dim3(512), dim3(256), 0, stream>>>(spk, noise, g_w, g_b, b_w, b_b,
      tl_g_w, tl_g_b, tl_b_w, tl_b_b, gammas, betas);
  k_embed<<<dim3(9600), dim3(256), 0, stream>>>(inputs, emb, x);

  auto ccbn = [&](const float* in, float* outp, int idx) {
    k_stats1<<<dim3(192), dim3(256), 0, stream>>>(in, part);
    k_stats2<<<dim3(1), dim3(256), 0, stream>>>(part, musr);
    k_normrelu<<<dim3(9600), dim3(256), 0, stream>>>(in, outp, musr,
        gammas + idx*4096, betas + idx*4096);
  };

  const int dils[3] = {1, 2, 4};
  for (int blk = 0; blk < 10; ++blk) {
    for (int j = 0; j < 3; ++j) {
      const float* cin = (j == 0) ? x : A;
      ccbn(cin, Bf, blk*3 + j);
      int mode = (j == 2) ? 1 : 0;
      float* cout = (j == 2) ? x : A;   // third conv accumulates residual into x
      k_conv<5><<<dim3(160, 4), dim3(256), 0, stream>>>(Bf, cout,
          conv_w + (size_t)(blk*3 + j)*327680, conv_b + (blk*3 + j)*256, dils[j], mode);
    }
  }
  // token-length head
  ccbn(x, Bf, 30);
  k_conv<1><<<dim3(160, 4), dim3(256), 0, stream>>>(Bf, A, tl_c1_w, tl_c1_b, 1, 0);
  ccbn(A, Bf, 31);
  k_tl2<<<dim3(2400), dim3(256), 0, stream>>>(Bf, tl_c2_w, tl_c2_b, tl);
  k_cumsum<<<dim3(16), dim3(64), 0, stream>>>(tl, cen, out + 24576000);
  // alignment einsum
  k_align<<<dim3(250, 16), dim3(256), 0, stream>>>(x, cen, out);
}

// Round 3
// 4500.143 us; speedup vs baseline: 1.1059x; 1.1059x over previous
//
#include <hip/hip_runtime.h>
#include <math.h>

#define EPSv 1e-5f

typedef short short8 __attribute__((ext_vector_type(8)));
typedef float floatx4 __attribute__((ext_vector_type(4)));

__device__ __forceinline__ unsigned short f2bf(float x) {
  unsigned u = __float_as_uint(x);
  unsigned r = (u + 0x7fffu + ((u >> 16) & 1u)) >> 16;
  return (unsigned short)r;
}

// ---------------- gamma/beta for all 32 CCBNs (reads each W once) ----------------
__global__ void k_gamma_beta(const float* __restrict__ spk, const float* __restrict__ noise,
                             const float* __restrict__ g_w, const float* __restrict__ g_b,
                             const float* __restrict__ b_w, const float* __restrict__ b_b,
                             const float* __restrict__ tl_g_w, const float* __restrict__ tl_g_b,
                             const float* __restrict__ tl_b_w, const float* __restrict__ tl_b_b,
                             float* __restrict__ gammas, float* __restrict__ betas) {
  __shared__ float condl[16*256];
  int t = threadIdx.x;
  for (int idx = t; idx < 4096; idx += 256) {
    int b = idx >> 8, k = idx & 255;
    condl[idx] = (k < 128) ? spk[b*128 + k] : noise[b*128 + k - 128];
  }
  __syncthreads();
  int i = blockIdx.x;   // ccbn index 0..31
  const float *gw, *bw, *gbias, *bbias;
  if (i < 30) { gw = g_w + (size_t)i*65536; bw = b_w + (size_t)i*65536; gbias = g_b + i*256; bbias = b_b + i*256; }
  else { int j = i - 30; gw = tl_g_w + (size_t)j*65536; bw = tl_b_w + (size_t)j*65536; gbias = tl_g_b + j*256; bbias = tl_b_b + j*256; }
  int co = (t & 63) + blockIdx.y * 64;
  int slot = t >> 6;     // handles b = slot*4 .. slot*4+3
  float g[4] = {0.f,0.f,0.f,0.f}, bt[4] = {0.f,0.f,0.f,0.f};
  for (int k = 0; k < 256; ++k) {
    float gwv = gw[k*256 + co];
    float bwv = bw[k*256 + co];
    #pragma unroll
    for (int bb = 0; bb < 4; ++bb) {
      float cv = condl[(slot*4 + bb)*256 + k];
      g[bb]  = fmaf(cv, gwv, g[bb]);
      bt[bb] = fmaf(cv, bwv, bt[bb]);
    }
  }
  #pragma unroll
  for (int bb = 0; bb < 4; ++bb) {
    int b = slot*4 + bb;
    gammas[i*4096 + b*256 + co] = 1.0f + g[bb] + gbias[co];
    betas [i*4096 + b*256 + co] = bt[bb] + bbias[co];
  }
}

// ---------------- embedding gather ----------------
__global__ void k_embed(const int* __restrict__ inp, const float* __restrict__ emb,
                        float* __restrict__ x) {
  int r = blockIdx.x;
  int c = threadIdx.x;
  int row = inp[r];
  x[(size_t)r*256 + c] = emb[(size_t)row*256 + c];
}

// ---------------- CCBN stats (two-pass) ----------------
__global__ void k_stats1(const float* __restrict__ in, float* __restrict__ part) {
  int blk = blockIdx.x; int c = threadIdx.x;   // 192 blocks x 50 rows
  float s = 0.f, s2 = 0.f;
  int r0 = blk * 50;
  for (int r = r0; r < r0 + 50; ++r) {
    float v = in[(size_t)r*256 + c];
    s += v; s2 = fmaf(v, v, s2);
  }
  part[blk*512 + c] = s;
  part[blk*512 + 256 + c] = s2;
}

// finalize stats + fold gamma/beta into per-(b,c) scale/shift
__global__ void k_stats2b(const float* __restrict__ part,
                          const float* __restrict__ gammas, const float* __restrict__ betas,
                          float* __restrict__ scsh) {
  int c = threadIdx.x; int b = blockIdx.x;
  float s = 0.f, s2 = 0.f;
  for (int g = 0; g < 192; ++g) { s += part[g*512 + c]; s2 += part[g*512 + 256 + c]; }
  float mu = s * (1.0f/9600.0f);
  float var = s2 * (1.0f/9600.0f) - mu*mu;
  float rs = rsqrtf(var + EPSv);
  float scale = rs * gammas[b*256 + c];
  scsh[b*256 + c] = scale;
  scsh[4096 + b*256 + c] = fmaf(-mu, scale, betas[b*256 + c]);
}

// ---------------- dilated conv as tiled GEMM, CCBN+ReLU fused at staging ----------------
// NOTE: never run in-place (cin != cout): every block reads all channels of its
// l-range (+halo) while others write their co-tiles — in-place races (R2 bug).
template<int K>
__global__ __launch_bounds__(256) void k_conv(const float* __restrict__ zin, float* __restrict__ out,
                       const float* __restrict__ scsh,
                       const float* __restrict__ w, const float* __restrict__ bias,
                       int dil, int mode) {
  __shared__ float Zt[80*20];
  __shared__ float Wt[16*K*64];
  int t = threadIdx.x;
  int b  = blockIdx.x / 10;
  int l0 = (blockIdx.x % 10) * 64;
  int co0 = blockIdx.y * 64;
  int PAD = ((K-1)/2) * dil;
  int ROWS = 64 + 2*PAD;
  int rt = t >> 4, ct = t & 15;
  float acc[4][4] = {{0.f}};
  const float* zb = zin + (size_t)b*600*256;
  const float* scb = scsh + b*256;
  const float* shb = scsh + 4096 + b*256;

  for (int ci0 = 0; ci0 < 256; ci0 += 16) {
    __syncthreads();
    for (int idx = t; idx < ROWS*16; idx += 256) {
      int row = idx >> 4, j = idx & 15;
      int gl = l0 + row - PAD;
      float v = 0.f;
      if (gl >= 0 && gl < 600) {
        int cc = ci0 + j;
        v = fmaxf(fmaf(zb[(size_t)gl*256 + cc], scb[cc], shb[cc]), 0.f);
      }
      Zt[row*20 + j] = v;
    }
    {
      int coi = t >> 2, q = t & 3;
      const float* wsrc = w + ((size_t)(co0 + coi) * 256 + ci0) * K + q * 4 * K;
      #pragma unroll
      for (int m4 = 0; m4 < K; ++m4) {
        float4 v = *(const float4*)(wsrc + m4*4);
        float vv[4] = {v.x, v.y, v.z, v.w};
        #pragma unroll
        for (int comp = 0; comp < 4; ++comp) {
          int e = q*4*K + m4*4 + comp;
          int j = e / K, k = e % K;
          Wt[(j*K + k)*64 + coi] = vv[comp];
        }
      }
    }
    __syncthreads();
    for (int k = 0; k < K; ++k) {
      int rbase = k * dil;
      #pragma unroll
      for (int jj = 0; jj < 16; jj += 4) {
        float4 zv[4]; float4 wv[4];
        #pragma unroll
        for (int i = 0; i < 4; ++i)
          zv[i] = *(const float4*)&Zt[(rt*4 + i + rbase)*20 + jj];
        #pragma unroll
        for (int q = 0; q < 4; ++q)
          wv[q] = *(const float4*)&Wt[((jj + q)*K + k)*64 + ct*4];
        #pragma unroll
        for (int i = 0; i < 4; ++i) {
          const float* zi = (const float*)&zv[i];
          #pragma unroll
          for (int q = 0; q < 4; ++q) {
            float zq = zi[q];
            acc[i][0] = fmaf(zq, wv[q].x, acc[i][0]);
            acc[i][1] = fmaf(zq, wv[q].y, acc[i][1]);
            acc[i][2] = fmaf(zq, wv[q].z, acc[i][2]);
            acc[i][3] = fmaf(zq, wv[q].w, acc[i][3]);
          }
        }
      }
    }
  }
  float4 bi = *(const float4*)&bias[co0 + ct*4];
  #pragma unroll
  for (int i = 0; i < 4; ++i) {
    int l = l0 + rt*4 + i;
    if (l < 600) {
      float4 v;
      v.x = acc[i][0] + bi.x; v.y = acc[i][1] + bi.y;
      v.z = acc[i][2] + bi.z; v.w = acc[i][3] + bi.w;
      float4* dst = (float4*)&out[((size_t)(b*600 + l))*256 + co0 + ct*4];
      if (mode) { float4 o = *dst; v.x += o.x; v.y += o.y; v.z += o.z; v.w += o.w; }
      *dst = v;
    }
  }
}

// ---------------- token-length final 256->1 conv + relu (CCBN fused) ----------------
__global__ void k_tl2(const float* __restrict__ z, const float* __restrict__ scsh,
                      const float* __restrict__ w2, const float* __restrict__ b2,
                      float* __restrict__ tl) {
  int t = threadIdx.x;
  int row = blockIdx.x * 4 + (t >> 6);
  int lane = t & 63;
  int b = row / 600;
  float4 zr = *(const float4*)&z[(size_t)row*256 + lane*4];
  float4 sc = *(const float4*)&scsh[b*256 + lane*4];
  float4 sh = *(const float4*)&scsh[4096 + b*256 + lane*4];
  float4 wr = *(const float4*)&w2[lane*4];
  float z0 = fmaxf(fmaf(zr.x, sc.x, sh.x), 0.f);
  float z1 = fmaxf(fmaf(zr.y, sc.y, sh.y), 0.f);
  float z2 = fmaxf(fmaf(zr.z, sc.z, sh.z), 0.f);
  float z3 = fmaxf(fmaf(zr.w, sc.w, sh.w), 0.f);
  float s = z0*wr.x + z1*wr.y + z2*wr.z + z3*wr.w;
  for (int m = 32; m >= 1; m >>= 1) s += __shfl_xor(s, m, 64);
  if (lane == 0) tl[row] = fmaxf(s + b2[0], 0.f);
}

// ---------------- per-batch cumsum -> ends (output 1) + centers ----------------
__global__ void k_cumsum(const float* __restrict__ tl, float* __restrict__ centers,
                         float* __restrict__ out_len) {
  int b = blockIdx.x; int lane = threadIdx.x;
  float carry = 0.f;
  for (int ch = 0; ch < 10; ++ch) {
    int l = ch*64 + lane;
    float v = (l < 600) ? tl[b*600 + l] : 0.f;
    float s = v;
    #pragma unroll
    for (int off = 1; off < 64; off <<= 1) {
      float n = __shfl_up(s, off, 64);
      if (lane >= off) s += n;
    }
    float ends = carry + s;
    if (l < 600) {
      centers[b*600 + l] = ends - 0.5f*v;
      out_len[b*600 + l] = ends;
    }
    carry = __shfl(ends, 63, 64);
  }
}

// ---------------- fp32 (b,l,c) -> bf16 (b,c,l) transpose, l padded to 640 ----------------
__global__ void k_tobf16(const float* __restrict__ x, unsigned short* __restrict__ fbT) {
  __shared__ unsigned short T[64*66];
  int b = blockIdx.x, lt = blockIdx.y, ct = blockIdx.z;
  int t = threadIdx.x;
  int i4 = t >> 6;          // 0..3
  int j = t & 63;           // c-sub
  #pragma unroll
  for (int r = 0; r < 16; ++r) {
    int li = i4*16 + r;
    int l = lt*64 + li;
    float v = (l < 600) ? x[((size_t)(b*600 + l))*256 + ct*64 + j] : 0.f;
    T[j*66 + li] = f2bf(v);
  }
  __syncthreads();
  int row = t >> 2, seg = (t & 3) * 16;
  unsigned vv[8];
  #pragma unroll
  for (int k = 0; k < 8; ++k)
    vv[k] = *(const unsigned*)&T[row*66 + seg + k*2];
  size_t dsth = ((size_t)(b*256 + ct*64 + row))*640 + lt*64 + seg;  // in halves (even)
  unsigned* du = (unsigned*)fbT;
  uint4 a; a.x = vv[0]; a.y = vv[1]; a.z = vv[2]; a.w = vv[3];
  uint4 c4; c4.x = vv[4]; c4.y = vv[5]; c4.z = vv[6]; c4.w = vv[7];
  *(uint4*)(du + dsth/2) = a;
  *(uint4*)(du + dsth/2 + 4) = c4;
}

// ---------------- alignment einsum via bf16 MFMA ----------------
__global__ __launch_bounds__(256) void k_align2(const unsigned short* __restrict__ fbT,
                        const float* __restrict__ centers, float* __restrict__ outp) {
  __shared__ float cen[600];
  __shared__ float mrow[64];
  __shared__ float isum[64];
  __shared__ unsigned short Wt[64*72];
  __shared__ unsigned short Ft[256*72];
  int b = blockIdx.x;
  int o0 = blockIdx.y * 64;
  int t = threadIdx.x;
  int wv = t >> 6, lane = t & 63;
  for (int i = t; i < 600; i += 256) cen[i] = centers[b*600 + i];
  __syncthreads();
  // phase 1: per-o-row max and 1/sum
  for (int rr = 0; rr < 16; ++rr) {
    int oi = wv*16 + rr;
    float opos = (float)(o0 + oi);
    float mx = -3.0e38f;
    for (int l = lane; l < 600; l += 64) {
      float d = cen[l] - opos;
      mx = fmaxf(mx, -d*d*0.1f);
    }
    #pragma unroll
    for (int mm = 32; mm >= 1; mm >>= 1) mx = fmaxf(mx, __shfl_xor(mx, mm, 64));
    float sum = 0.f;
    for (int l = lane; l < 600; l += 64) {
      float d = cen[l] - opos;
      sum += __expf(-d*d*0.1f - mx);
    }
    #pragma unroll
    for (int mm = 32; mm >= 1; mm >>= 1) sum += __shfl_xor(sum, mm, 64);
    if (lane == 0) { mrow[oi] = mx; isum[oi] = 1.0f / sum; }
  }
  __syncthreads();
  floatx4 acc[4][4];
  #pragma unroll
  for (int i = 0; i < 4; ++i)
    #pragma unroll
    for (int j = 0; j < 4; ++j)
      acc[i][j] = (floatx4){0.f, 0.f, 0.f, 0.f};
  int quad = lane >> 4;
  int nlan = lane & 15;
  int oi_w = t >> 2;               // weight-staging row
  int lq = (t & 3) * 16;
  float mo = mrow[oi_w];
  float opos_w = (float)(o0 + oi_w);
  const unsigned short* srcb = fbT + ((size_t)b*256)*640;

  for (int ch = 0; ch < 10; ++ch) {
    int lc0 = ch * 64;
    __syncthreads();
    #pragma unroll
    for (int jj = 0; jj < 16; jj += 2) {
      int l0i = lc0 + lq + jj;
      float e0 = 0.f, e1 = 0.f;
      if (l0i < 600)     { float d = cen[l0i] - opos_w;     e0 = __expf(-d*d*0.1f - mo); }
      if (l0i + 1 < 600) { float d = cen[l0i + 1] - opos_w; e1 = __expf(-d*d*0.1f - mo); }
      unsigned pk = (unsigned)f2bf(e0) | ((unsigned)f2bf(e1) << 16);
      *(unsigned*)&Wt[oi_w*72 + lq + jj] = pk;
    }
    #pragma unroll
    for (int it = 0; it < 8; ++it) {
      int idx = t + it*256;
      int c = idx >> 3, part = idx & 7;
      uint4 v = *(const uint4*)(srcb + (size_t)c*640 + lc0 + part*8);
      *(uint4*)&Ft[c*72 + part*8] = v;
    }
    __syncthreads();
    #pragma unroll
    for (int ks = 0; ks < 2; ++ks) {
      int ko = ks*32 + quad*8;
      short8 af[4], bfr[4];
      #pragma unroll
      for (int mt = 0; mt < 4; ++mt)
        af[mt] = *(const short8*)&Wt[(mt*16 + nlan)*72 + ko];
      #pragma unroll
      for (int nt = 0; nt < 4; ++nt)
        bfr[nt] = *(const short8*)&Ft[(wv*64 + nt*16 + nlan)*72 + ko];
      #pragma unroll
      for (int mt = 0; mt < 4; ++mt)
        #pragma unroll
        for (int nt = 0; nt < 4; ++nt)
          acc[mt][nt] = __builtin_amdgcn_mfma_f32_16x16x32_bf16(af[mt], bfr[nt], acc[mt][nt], 0, 0, 0);
    }
  }
  #pragma unroll
  for (int mt = 0; mt < 4; ++mt) {
    #pragma unroll
    for (int r = 0; r < 4; ++r) {
      int oi = mt*16 + quad*4 + r;
      int o = o0 + oi;
      if (o < 6000) {
        float sc = isum[oi];
        #pragma unroll
        for (int nt = 0; nt < 4; ++nt) {
          int c = wv*64 + nt*16 + nlan;
          outp[((size_t)b*6000 + o)*256 + c] = acc[mt][nt][r] * sc;
        }
      }
    }
  }
}

extern "C" void kernel_launch(void* const* d_in, const int* in_sizes, int n_in,
                              void* d_out, int out_size, void* d_ws, size_t ws_size,
                              hipStream_t stream) {
  const int*   inputs = (const int*)  d_in[0];
  const float* spk    = (const float*)d_in[1];
  const float* noise  = (const float*)d_in[2];
  const float* emb    = (const float*)d_in[3];
  const float* conv_w = (const float*)d_in[4];
  const float* conv_b = (const float*)d_in[5];
  const float* g_w    = (const float*)d_in[6];
  const float* g_b    = (const float*)d_in[7];
  const float* b_w    = (const float*)d_in[8];
  const float* b_b    = (const float*)d_in[9];
  const float* tl_g_w = (const float*)d_in[10];
  const float* tl_g_b = (const float*)d_in[11];
  const float* tl_b_w = (const float*)d_in[12];
  const float* tl_b_b = (const float*)d_in[13];
  const float* tl_c1_w = (const float*)d_in[14];
  const float* tl_c1_b = (const float*)d_in[15];
  const float* tl_c2_w = (const float*)d_in[16];
  const float* tl_c2_b = (const float*)d_in[17];
  float* out = (float*)d_out;

  float* ws = (float*)d_ws;
  float* x      = ws;                 // 2457600
  float* A      = x + 2457600;        // 2457600
  float* Bf     = A + 2457600;        // 2457600 (also reused as fbT at the end)
  float* gammas = Bf + 2457600;       // 131072
  float* betas  = gammas + 131072;    // 131072
  float* part   = betas + 131072;     // 98304
  float* scsh   = part + 98304;       // 8192
  float* tl     = scsh + 8192;        // 9600
  float* cen    = tl + 9600;          // 9600
  unsigned short* fbT = (unsigned short*)Bf;  // 16*256*640 halves = 5.2 MB, Bf is dead by then

  k_gamma_beta<<<dim3(32, 4), dim3(256), 0, stream>>>(spk, noise, g_w, g_b, b_w, b_b,
      tl_g_w, tl_g_b, tl_b_w, tl_b_b, gammas, betas);
  k_embed<<<dim3(9600), dim3(256), 0, stream>>>(inputs, emb, x);

  auto ccbn = [&](const float* in, int idx) {
    k_stats1<<<dim3(192), dim3(256), 0, stream>>>(in, part);
    k_stats2b<<<dim3(16), dim3(256), 0, stream>>>(part, gammas + idx*4096, betas + idx*4096, scsh);
  };

  const int dils[3] = {1, 2, 4};
  for (int blk = 0; blk < 10; ++blk) {
    // ping-pong: x -> A -> Bf -> x(+residual); never in-place (R2 race)
    const float* srcs[3] = {x, A, Bf};
    float*       dsts[3] = {A, Bf, x};
    for (int j = 0; j < 3; ++j) {
      const float* cin = srcs[j];
      ccbn(cin, blk*3 + j);
      int mode = (j == 2) ? 1 : 0;
      k_conv<5><<<dim3(160, 4), dim3(256), 0, stream>>>(cin, dsts[j], scsh,
          conv_w + (size_t)(blk*3 + j)*327680, conv_b + (blk*3 + j)*256, dils[j], mode);
    }
  }
  // token-length head
  ccbn(x, 30);
  k_conv<1><<<dim3(160, 4), dim3(256), 0, stream>>>(x, A, scsh, tl_c1_w, tl_c1_b, 1, 0);
  ccbn(A, 31);
  k_tl2<<<dim3(2400), dim3(256), 0, stream>>>(A, scsh, tl_c2_w, tl_c2_b, tl);
  k_cumsum<<<dim3(16), dim3(64), 0, stream>>>(tl, cen, out + 24576000);
  // alignment einsum (bf16 MFMA)
  k_tobf16<<<dim3(16, 10, 4), dim3(256), 0, stream>>>(x, fbT);
  k_align2<<<dim3(16, 94), dim3(256), 0, stream>>>(fbT, cen, out);
}

// Round 5
// 2149.325 us; speedup vs baseline: 2.3154x; 2.0937x over previous
//
#include <hip/hip_runtime.h>
#include <math.h>

#define EPSv 1e-5f

typedef short short8 __attribute__((ext_vector_type(8)));
typedef float floatx4 __attribute__((ext_vector_type(4)));

__device__ __forceinline__ unsigned short f2bf(float x) {
  unsigned u = __float_as_uint(x);
  unsigned r = (u + 0x7fffu + ((u >> 16) & 1u)) >> 16;
  return (unsigned short)r;
}

// ---------------- gamma/beta for all 32 CCBNs ----------------
__global__ void k_gamma_beta(const float* __restrict__ spk, const float* __restrict__ noise,
                             const float* __restrict__ g_w, const float* __restrict__ g_b,
                             const float* __restrict__ b_w, const float* __restrict__ b_b,
                             const float* __restrict__ tl_g_w, const float* __restrict__ tl_g_b,
                             const float* __restrict__ tl_b_w, const float* __restrict__ tl_b_b,
                             float* __restrict__ gammas, float* __restrict__ betas) {
  __shared__ float condl[16*256];
  int t = threadIdx.x;
  for (int idx = t; idx < 4096; idx += 256) {
    int b = idx >> 8, k = idx & 255;
    condl[idx] = (k < 128) ? spk[b*128 + k] : noise[b*128 + k - 128];
  }
  __syncthreads();
  int i = blockIdx.x;
  const float *gw, *bw, *gbias, *bbias;
  if (i < 30) { gw = g_w + (size_t)i*65536; bw = b_w + (size_t)i*65536; gbias = g_b + i*256; bbias = b_b + i*256; }
  else { int j = i - 30; gw = tl_g_w + (size_t)j*65536; bw = tl_b_w + (size_t)j*65536; gbias = tl_g_b + j*256; bbias = tl_b_b + j*256; }
  int co = (t & 63) + blockIdx.y * 64;
  int slot = t >> 6;
  float g[4] = {0.f,0.f,0.f,0.f}, bt[4] = {0.f,0.f,0.f,0.f};
  for (int k = 0; k < 256; ++k) {
    float gwv = gw[k*256 + co];
    float bwv = bw[k*256 + co];
    #pragma unroll
    for (int bb = 0; bb < 4; ++bb) {
      float cv = condl[(slot*4 + bb)*256 + k];
      g[bb]  = fmaf(cv, gwv, g[bb]);
      bt[bb] = fmaf(cv, bwv, bt[bb]);
    }
  }
  #pragma unroll
  for (int bb = 0; bb < 4; ++bb) {
    int b = slot*4 + bb;
    gammas[i*4096 + b*256 + co] = 1.0f + g[bb] + gbias[co];
    betas [i*4096 + b*256 + co] = bt[bb] + bbias[co];
  }
}

// ---------------- weight prepack: fp32 (co,ci,k) -> bf16 hi/lo in B-fragment order ----------------
// layout per conv: [cotile(4)][chunk(8)][tap][plane(2)][co64][ci32] halves
__global__ void k_wprep(const float* __restrict__ conv_w, const float* __restrict__ tl_c1_w,
                        unsigned short* __restrict__ wp) {
  int cc = blockIdx.x; int cotile = blockIdx.y; int t = threadIdx.x;
  int TAPS = (cc == 30) ? 1 : 5;
  const float* src = (cc == 30) ? tl_c1_w : conv_w + (size_t)cc*327680;
  unsigned short* dst = wp + ((cc == 30) ? (size_t)30*655360 : (size_t)cc*655360);
  int n = 64*256*TAPS;
  for (int idx = t; idx < n; idx += 256) {
    int tap = idx % TAPS; int rem = idx / TAPS; int ci = rem & 255; int cow = rem >> 8;
    float v = src[(((size_t)(cotile*64 + cow))*256 + ci)*TAPS + tap];
    unsigned short hi = f2bf(v);
    float hif = __uint_as_float((unsigned)hi << 16);
    unsigned short lo = f2bf(v - hif);
    size_t o = (size_t)cotile*(8*TAPS*4096) + (size_t)(ci >> 5)*(TAPS*4096)
             + (size_t)(tap*2)*2048 + cow*32 + (ci & 31);
    dst[o] = hi;
    dst[o + 2048] = lo;
  }
}

// ---------------- embedding gather + fused stats partials ----------------
__global__ void k_embed2(const int* __restrict__ inp, const float* __restrict__ emb,
                         float* __restrict__ x, float* __restrict__ part2) {
  int bx = blockIdx.x;            // 160 blocks x 60 rows
  int c = threadIdx.x;
  int r0 = bx * 60;
  float s = 0.f, s2 = 0.f;
  for (int r = 0; r < 60; ++r) {
    int row = inp[r0 + r];
    float v = emb[(size_t)row*256 + c];
    x[(size_t)(r0 + r)*256 + c] = v;
    s += v; s2 = fmaf(v, v, s2);
  }
  part2[bx*512 + c] = s;
  part2[bx*512 + 256 + c] = s2;
}

// ---------------- finalize stats from 160 partials + fold gamma/beta ----------------
__global__ void k_stats2f(const float* __restrict__ part2,
                          const float* __restrict__ gammas, const float* __restrict__ betas,
                          float* __restrict__ scsh) {
  int c = threadIdx.x; int b = blockIdx.x;
  float s = 0.f, s2 = 0.f;
  for (int g = 0; g < 160; ++g) { s += part2[g*512 + c]; s2 += part2[g*512 + 256 + c]; }
  float mu = s * (1.0f/9600.0f);
  float var = s2 * (1.0f/9600.0f) - mu*mu;
  float rs = rsqrtf(var + EPSv);
  float scale = rs * gammas[b*256 + c];
  scsh[b*256 + c] = scale;
  scsh[4096 + b*256 + c] = fmaf(-mu, scale, betas[b*256 + c]);
}

// ---------------- MFMA dilated conv: CCBN+ReLU fused staging, bf16x2 split, stats in epilogue ----
// block = 64l x 64co, 4 waves of 32l x 32co. Z in LDS (pitch 40 halves).
// W read directly from prepacked global in exact B-fragment order (L2-hot, no LDS, no barrier).
// CRITICAL (R4 bug): out-of-range rows must stage EXACT ZERO (conv SAME padding),
// not relu(shift) — predicate the post-BN value, not just the load.
template<int TAPS>
__global__ __launch_bounds__(256) void k_convm(const float* __restrict__ zin, float* __restrict__ out,
                        const float* __restrict__ scsh, const unsigned short* __restrict__ wpc,
                        const float* __restrict__ bias, int dil, int mode,
                        float* __restrict__ part2) {
  __shared__ unsigned short Zhi[80*40];
  __shared__ unsigned short Zlo[80*40];
  __shared__ float lsum[64];
  __shared__ float lsq[64];
  int t = threadIdx.x;
  int bx = blockIdx.x;
  int b  = bx / 10;
  int l0 = (bx % 10) * 64;
  int co0 = blockIdx.y * 64;
  int PAD = ((TAPS - 1)/2) * dil;
  int ROWS = 64 + 2*PAD;
  int w = t >> 6, lane = t & 63;
  int lsub = (w & 1) * 32, cosub = (w >> 1) * 32;
  int quad = lane >> 4, nlan = lane & 15;
  if (t < 64) { lsum[t] = 0.f; lsq[t] = 0.f; }

  floatx4 acc[2][2];
  #pragma unroll
  for (int i = 0; i < 2; ++i)
    #pragma unroll
    for (int j = 0; j < 2; ++j) acc[i][j] = (floatx4){0.f,0.f,0.f,0.f};

  const float* zb = zin + (size_t)b*600*256;
  int srow = t >> 3, fq = t & 7;
  float4 sc4 = {0,0,0,0}, sh4 = {0,0,0,0};
  int ar0 = (lsub + nlan) * 40 + quad * 8;
  int ar1 = (lsub + 16 + nlan) * 40 + quad * 8;

  for (int chunk = 0; chunk < 8; ++chunk) {
    int ci0 = chunk * 32;
    const unsigned short* pch = wpc + (size_t)(blockIdx.y*8 + chunk) * (TAPS*4096);
    short8 bh[TAPS][2], bl[TAPS][2];
    #pragma unroll
    for (int tap = 0; tap < TAPS; ++tap) {
      #pragma unroll
      for (int nt = 0; nt < 2; ++nt) {
        int cw = (cosub + nt*16 + nlan)*32 + quad*8;
        bh[tap][nt] = *(const short8*)(pch + (size_t)(tap*2)*2048 + cw);
        bl[tap][nt] = *(const short8*)(pch + (size_t)(tap*2+1)*2048 + cw);
      }
    }
    sc4 = *(const float4*)&scsh[b*256 + ci0 + fq*4];
    sh4 = *(const float4*)&scsh[4096 + b*256 + ci0 + fq*4];
    __syncthreads();   // previous chunk's A-reads done before overwrite
    for (int r = srow; r < ROWS; r += 32) {
      int gl = l0 - PAD + r;
      bool inr = (gl >= 0 && gl < 600);
      float4 z = {0,0,0,0};
      if (inr) z = *(const float4*)&zb[(size_t)gl*256 + ci0 + fq*4];
      // SAME padding: rows outside [0,600) must contribute exact zero
      float v0 = inr ? fmaxf(fmaf(z.x, sc4.x, sh4.x), 0.f) : 0.f;
      float v1 = inr ? fmaxf(fmaf(z.y, sc4.y, sh4.y), 0.f) : 0.f;
      float v2 = inr ? fmaxf(fmaf(z.z, sc4.z, sh4.z), 0.f) : 0.f;
      float v3 = inr ? fmaxf(fmaf(z.w, sc4.w, sh4.w), 0.f) : 0.f;
      unsigned short h0 = f2bf(v0), h1 = f2bf(v1), h2 = f2bf(v2), h3 = f2bf(v3);
      unsigned short e0 = f2bf(v0 - __uint_as_float((unsigned)h0 << 16));
      unsigned short e1 = f2bf(v1 - __uint_as_float((unsigned)h1 << 16));
      unsigned short e2 = f2bf(v2 - __uint_as_float((unsigned)h2 << 16));
      unsigned short e3 = f2bf(v3 - __uint_as_float((unsigned)h3 << 16));
      uint2 vh; vh.x = (unsigned)h0 | ((unsigned)h1 << 16);
      vh.y = (unsigned)h2 | ((unsigned)h3 << 16);
      uint2 vl; vl.x = (unsigned)e0 | ((unsigned)e1 << 16);
      vl.y = (unsigned)e2 | ((unsigned)e3 << 16);
      *(uint2*)&Zhi[r*40 + fq*4] = vh;
      *(uint2*)&Zlo[r*40 + fq*4] = vl;
    }
    __syncthreads();
    #pragma unroll
    for (int tap = 0; tap < TAPS; ++tap) {
      int sh = tap * dil * 40;
      short8 ah0 = *(const short8*)&Zhi[ar0 + sh];
      short8 ah1 = *(const short8*)&Zhi[ar1 + sh];
      short8 al0 = *(const short8*)&Zlo[ar0 + sh];
      short8 al1 = *(const short8*)&Zlo[ar1 + sh];
      #pragma unroll
      for (int nt = 0; nt < 2; ++nt) {
        acc[0][nt] = __builtin_amdgcn_mfma_f32_16x16x32_bf16(ah0, bh[tap][nt], acc[0][nt], 0, 0, 0);
        acc[0][nt] = __builtin_amdgcn_mfma_f32_16x16x32_bf16(ah0, bl[tap][nt], acc[0][nt], 0, 0, 0);
        acc[0][nt] = __builtin_amdgcn_mfma_f32_16x16x32_bf16(al0, bh[tap][nt], acc[0][nt], 0, 0, 0);
        acc[1][nt] = __builtin_amdgcn_mfma_f32_16x16x32_bf16(ah1, bh[tap][nt], acc[1][nt], 0, 0, 0);
        acc[1][nt] = __builtin_amdgcn_mfma_f32_16x16x32_bf16(ah1, bl[tap][nt], acc[1][nt], 0, 0, 0);
        acc[1][nt] = __builtin_amdgcn_mfma_f32_16x16x32_bf16(al1, bh[tap][nt], acc[1][nt], 0, 0, 0);
      }
    }
  }

  // epilogue: bias (+residual), store, fused stats partials
  float bsv[2], ssum[2] = {0.f, 0.f}, ssq[2] = {0.f, 0.f};
  #pragma unroll
  for (int nt = 0; nt < 2; ++nt) bsv[nt] = bias[co0 + cosub + nt*16 + nlan];
  #pragma unroll
  for (int mt = 0; mt < 2; ++mt) {
    #pragma unroll
    for (int r = 0; r < 4; ++r) {
      int l = l0 + lsub + mt*16 + quad*4 + r;
      if (l < 600) {
        size_t rowo = ((size_t)(b*600 + l))*256 + co0 + cosub;
        #pragma unroll
        for (int nt = 0; nt < 2; ++nt) {
          float v = acc[mt][nt][r] + bsv[nt];
          float* dst = &out[rowo + nt*16 + nlan];
          if (mode) v += *dst;
          *dst = v;
          ssum[nt] += v;
          ssq[nt] = fmaf(v, v, ssq[nt]);
        }
      }
    }
  }
  #pragma unroll
  for (int nt = 0; nt < 2; ++nt) {
    ssum[nt] += __shfl_xor(ssum[nt], 16, 64);
    ssum[nt] += __shfl_xor(ssum[nt], 32, 64);
    ssq[nt]  += __shfl_xor(ssq[nt], 16, 64);
    ssq[nt]  += __shfl_xor(ssq[nt], 32, 64);
  }
  if (quad == 0) {
    #pragma unroll
    for (int nt = 0; nt < 2; ++nt) {
      atomicAdd(&lsum[cosub + nt*16 + nlan], ssum[nt]);
      atomicAdd(&lsq [cosub + nt*16 + nlan], ssq[nt]);
    }
  }
  __syncthreads();
  if (t < 64) {
    part2[bx*512 + co0 + t] = lsum[t];
    part2[bx*512 + 256 + co0 + t] = lsq[t];
  }
}

// ---------------- token-length final 256->1 conv + relu (CCBN fused) ----------------
__global__ void k_tl2(const float* __restrict__ z, const float* __restrict__ scsh,
                      const float* __restrict__ w2, const float* __restrict__ b2,
                      float* __restrict__ tl) {
  int t = threadIdx.x;
  int row = blockIdx.x * 4 + (t >> 6);
  int lane = t & 63;
  int b = row / 600;
  float4 zr = *(const float4*)&z[(size_t)row*256 + lane*4];
  float4 sc = *(const float4*)&scsh[b*256 + lane*4];
  float4 sh = *(const float4*)&scsh[4096 + b*256 + lane*4];
  float4 wr = *(const float4*)&w2[lane*4];
  float z0 = fmaxf(fmaf(zr.x, sc.x, sh.x), 0.f);
  float z1 = fmaxf(fmaf(zr.y, sc.y, sh.y), 0.f);
  float z2 = fmaxf(fmaf(zr.z, sc.z, sh.z), 0.f);
  float z3 = fmaxf(fmaf(zr.w, sc.w, sh.w), 0.f);
  float s = z0*wr.x + z1*wr.y + z2*wr.z + z3*wr.w;
  for (int m = 32; m >= 1; m >>= 1) s += __shfl_xor(s, m, 64);
  if (lane == 0) tl[row] = fmaxf(s + b2[0], 0.f);
}

// ---------------- per-batch cumsum -> ends (output 1) + centers ----------------
__global__ void k_cumsum(const float* __restrict__ tl, float* __restrict__ centers,
                         float* __restrict__ out_len) {
  int b = blockIdx.x; int lane = threadIdx.x;
  float carry = 0.f;
  for (int ch = 0; ch < 10; ++ch) {
    int l = ch*64 + lane;
    float v = (l < 600) ? tl[b*600 + l] : 0.f;
    float s = v;
    #pragma unroll
    for (int off = 1; off < 64; off <<= 1) {
      float n = __shfl_up(s, off, 64);
      if (lane >= off) s += n;
    }
    float ends = carry + s;
    if (l < 600) {
      centers[b*600 + l] = ends - 0.5f*v;
      out_len[b*600 + l] = ends;
    }
    carry = __shfl(ends, 63, 64);
  }
}

// ---------------- fp32 (b,l,c) -> bf16 (b,c,l) transpose, l padded to 640 ----------------
__global__ void k_tobf16(const float* __restrict__ x, unsigned short* __restrict__ fbT) {
  __shared__ unsigned short T[64*66];
  int b = blockIdx.x, lt = blockIdx.y, ct = blockIdx.z;
  int t = threadIdx.x;
  int i4 = t >> 6;
  int j = t & 63;
  #pragma unroll
  for (int r = 0; r < 16; ++r) {
    int li = i4*16 + r;
    int l = lt*64 + li;
    float v = (l < 600) ? x[((size_t)(b*600 + l))*256 + ct*64 + j] : 0.f;
    T[j*66 + li] = f2bf(v);
  }
  __syncthreads();
  int row = t >> 2, seg = (t & 3) * 16;
  unsigned vv[8];
  #pragma unroll
  for (int k = 0; k < 8; ++k)
    vv[k] = *(const unsigned*)&T[row*66 + seg + k*2];
  size_t dsth = ((size_t)(b*256 + ct*64 + row))*640 + lt*64 + seg;
  unsigned* du = (unsigned*)fbT;
  uint4 a; a.x = vv[0]; a.y = vv[1]; a.z = vv[2]; a.w = vv[3];
  uint4 c4; c4.x = vv[4]; c4.y = vv[5]; c4.z = vv[6]; c4.w = vv[7];
  *(uint4*)(du + dsth/2) = a;
  *(uint4*)(du + dsth/2 + 4) = c4;
}

// ---------------- alignment einsum via bf16 MFMA ----------------
__global__ __launch_bounds__(256) void k_align2(const unsigned short* __restrict__ fbT,
                        const float* __restrict__ centers, float* __restrict__ outp) {
  __shared__ float cen[600];
  __shared__ float mrow[64];
  __shared__ float isum[64];
  __shared__ unsigned short Wt[64*72];
  __shared__ unsigned short Ft[256*72];
  int b = blockIdx.x;
  int o0 = blockIdx.y * 64;
  int t = threadIdx.x;
  int wv = t >> 6, lane = t & 63;
  for (int i = t; i < 600; i += 256) cen[i] = centers[b*600 + i];
  __syncthreads();
  for (int rr = 0; rr < 16; ++rr) {
    int oi = wv*16 + rr;
    float opos = (float)(o0 + oi);
    float mx = -3.0e38f;
    for (int l = lane; l < 600; l += 64) {
      float d = cen[l] - opos;
      mx = fmaxf(mx, -d*d*0.1f);
    }
    #pragma unroll
    for (int mm = 32; mm >= 1; mm >>= 1) mx = fmaxf(mx, __shfl_xor(mx, mm, 64));
    float sum = 0.f;
    for (int l = lane; l < 600; l += 64) {
      float d = cen[l] - opos;
      sum += __expf(-d*d*0.1f - mx);
    }
    #pragma unroll
    for (int mm = 32; mm >= 1; mm >>= 1) sum += __shfl_xor(sum, mm, 64);
    if (lane == 0) { mrow[oi] = mx; isum[oi] = 1.0f / sum; }
  }
  __syncthreads();
  floatx4 acc[4][4];
  #pragma unroll
  for (int i = 0; i < 4; ++i)
    #pragma unroll
    for (int j = 0; j < 4; ++j)
      acc[i][j] = (floatx4){0.f, 0.f, 0.f, 0.f};
  int quad = lane >> 4;
  int nlan = lane & 15;
  int oi_w = t >> 2;
  int lq = (t & 3) * 16;
  float mo = mrow[oi_w];
  float opos_w = (float)(o0 + oi_w);
  const unsigned short* srcb = fbT + ((size_t)b*256)*640;

  for (int ch = 0; ch < 10; ++ch) {
    int lc0 = ch * 64;
    __syncthreads();
    #pragma unroll
    for (int jj = 0; jj < 16; jj += 2) {
      int l0i = lc0 + lq + jj;
      float e0 = 0.f, e1 = 0.f;
      if (l0i < 600)     { float d = cen[l0i] - opos_w;     e0 = __expf(-d*d*0.1f - mo); }
      if (l0i + 1 < 600) { float d = cen[l0i + 1] - opos_w; e1 = __expf(-d*d*0.1f - mo); }
      unsigned pk = (unsigned)f2bf(e0) | ((unsigned)f2bf(e1) << 16);
      *(unsigned*)&Wt[oi_w*72 + lq + jj] = pk;
    }
    #pragma unroll
    for (int it = 0; it < 8; ++it) {
      int idx = t + it*256;
      int c = idx >> 3, part = idx & 7;
      uint4 v = *(const uint4*)(srcb + (size_t)c*640 + lc0 + part*8);
      *(uint4*)&Ft[c*72 + part*8] = v;
    }
    __syncthreads();
    #pragma unroll
    for (int ks = 0; ks < 2; ++ks) {
      int ko = ks*32 + quad*8;
      short8 af[4], bfr[4];
      #pragma unroll
      for (int mt = 0; mt < 4; ++mt)
        af[mt] = *(const short8*)&Wt[(mt*16 + nlan)*72 + ko];
      #pragma unroll
      for (int nt = 0; nt < 4; ++nt)
        bfr[nt] = *(const short8*)&Ft[(wv*64 + nt*16 + nlan)*72 + ko];
      #pragma unroll
      for (int mt = 0; mt < 4; ++mt)
        #pragma unroll
        for (int nt = 0; nt < 4; ++nt)
          acc[mt][nt] = __builtin_amdgcn_mfma_f32_16x16x32_bf16(af[mt], bfr[nt], acc[mt][nt], 0, 0, 0);
    }
  }
  #pragma unroll
  for (int mt = 0; mt < 4; ++mt) {
    #pragma unroll
    for (int r = 0; r < 4; ++r) {
      int oi = mt*16 + quad*4 + r;
      int o = o0 + oi;
      if (o < 6000) {
        float sc = isum[oi];
        #pragma unroll
        for (int nt = 0; nt < 4; ++nt) {
          int c = wv*64 + nt*16 + nlan;
          outp[((size_t)b*6000 + o)*256 + c] = acc[mt][nt][r] * sc;
        }
      }
    }
  }
}

extern "C" void kernel_launch(void* const* d_in, const int* in_sizes, int n_in,
                              void* d_out, int out_size, void* d_ws, size_t ws_size,
                              hipStream_t stream) {
  const int*   inputs = (const int*)  d_in[0];
  const float* spk    = (const float*)d_in[1];
  const float* noise  = (const float*)d_in[2];
  const float* emb    = (const float*)d_in[3];
  const float* conv_w = (const float*)d_in[4];
  const float* conv_b = (const float*)d_in[5];
  const float* g_w    = (const float*)d_in[6];
  const float* g_b    = (const float*)d_in[7];
  const float* b_w    = (const float*)d_in[8];
  const float* b_b    = (const float*)d_in[9];
  const float* tl_g_w = (const float*)d_in[10];
  const float* tl_g_b = (const float*)d_in[11];
  const float* tl_b_w = (const float*)d_in[12];
  const float* tl_b_b = (const float*)d_in[13];
  const float* tl_c1_w = (const float*)d_in[14];
  const float* tl_c1_b = (const float*)d_in[15];
  const float* tl_c2_w = (const float*)d_in[16];
  const float* tl_c2_b = (const float*)d_in[17];
  float* out = (float*)d_out;

  float* ws = (float*)d_ws;
  float* x      = ws;                 // 2457600
  float* A      = x + 2457600;        // 2457600
  float* Bf     = A + 2457600;        // 2457600 (reused as fbT at the end)
  float* gammas = Bf + 2457600;       // 131072
  float* betas  = gammas + 131072;    // 131072
  float* part2  = betas + 131072;     // 160*512 = 81920
  float* scsh   = part2 + 81920;      // 8192
  float* tl     = scsh + 8192;        // 9600
  float* cen    = tl + 9600;          // 9600
  unsigned short* wp = (unsigned short*)(cen + 9600);   // ~39.6 MB
  unsigned short* fbT = (unsigned short*)Bf;

  k_wprep<<<dim3(31, 4), dim3(256), 0, stream>>>(conv_w, tl_c1_w, wp);
  k_gamma_beta<<<dim3(32, 4), dim3(256), 0, stream>>>(spk, noise, g_w, g_b, b_w, b_b,
      tl_g_w, tl_g_b, tl_b_w, tl_b_b, gammas, betas);
  k_embed2<<<dim3(160), dim3(256), 0, stream>>>(inputs, emb, x, part2);

  const int dils[3] = {1, 2, 4};
  for (int blk = 0; blk < 10; ++blk) {
    const float* srcs[3] = {x, A, Bf};
    float*       dsts[3] = {A, Bf, x};   // ping-pong; never in-place (R2 race)
    for (int j = 0; j < 3; ++j) {
      int idx = blk*3 + j;
      k_stats2f<<<dim3(16), dim3(256), 0, stream>>>(part2, gammas + idx*4096, betas + idx*4096, scsh);
      int mode = (j == 2) ? 1 : 0;
      k_convm<5><<<dim3(160, 4), dim3(256), 0, stream>>>(srcs[j], dsts[j], scsh,
          wp + (size_t)idx*655360, conv_b + idx*256, dils[j], mode, part2);
    }
  }
  // token-length head
  k_stats2f<<<dim3(16), dim3(256), 0, stream>>>(part2, gammas + 30*4096, betas + 30*4096, scsh);
  k_convm<1><<<dim3(160, 4), dim3(256), 0, stream>>>(x, A, scsh,
      wp + (size_t)30*655360, tl_c1_b, 1, 0, part2);
  k_stats2f<<<dim3(16), dim3(256), 0, stream>>>(part2, gammas + 31*4096, betas + 31*4096, scsh);
  k_tl2<<<dim3(2400), dim3(256), 0, stream>>>(A, scsh, tl_c2_w, tl_c2_b, tl);
  k_cumsum<<<dim3(16), dim3(64), 0, stream>>>(tl, cen, out + 24576000);
  // alignment einsum (bf16 MFMA)
  k_tobf16<<<dim3(16, 10, 4), dim3(256), 0, stream>>>(x, fbT);
  k_align2<<<dim3(16, 94), dim3(256), 0, stream>>>(fbT, cen, out);
}

// Round 6
// 1713.677 us; speedup vs baseline: 2.9040x; 1.2542x over previous
//
#include <hip/hip_runtime.h>
#include <math.h>

#define EPSv 1e-5f

typedef short short8 __attribute__((ext_vector_type(8)));
typedef float floatx4 __attribute__((ext_vector_type(4)));

__device__ __forceinline__ unsigned short f2bf(float x) {
  unsigned u = __float_as_uint(x);
  unsigned r = (u + 0x7fffu + ((u >> 16) & 1u)) >> 16;
  return (unsigned short)r;
}

// ---------------- zero the 32 stat-accumulator slots ----------------
__global__ void k_zero(float* __restrict__ p) {
  p[blockIdx.x * 256 + threadIdx.x] = 0.f;
}

// ---------------- gamma/beta for all 32 CCBNs ----------------
__global__ void k_gamma_beta(const float* __restrict__ spk, const float* __restrict__ noise,
                             const float* __restrict__ g_w, const float* __restrict__ g_b,
                             const float* __restrict__ b_w, const float* __restrict__ b_b,
                             const float* __restrict__ tl_g_w, const float* __restrict__ tl_g_b,
                             const float* __restrict__ tl_b_w, const float* __restrict__ tl_b_b,
                             float* __restrict__ gammas, float* __restrict__ betas) {
  __shared__ float condl[16*256];
  int t = threadIdx.x;
  for (int idx = t; idx < 4096; idx += 256) {
    int b = idx >> 8, k = idx & 255;
    condl[idx] = (k < 128) ? spk[b*128 + k] : noise[b*128 + k - 128];
  }
  __syncthreads();
  int i = blockIdx.x;
  const float *gw, *bw, *gbias, *bbias;
  if (i < 30) { gw = g_w + (size_t)i*65536; bw = b_w + (size_t)i*65536; gbias = g_b + i*256; bbias = b_b + i*256; }
  else { int j = i - 30; gw = tl_g_w + (size_t)j*65536; bw = tl_b_w + (size_t)j*65536; gbias = tl_g_b + j*256; bbias = tl_b_b + j*256; }
  int co = (t & 63) + blockIdx.y * 64;
  int slot = t >> 6;
  float g[4] = {0.f,0.f,0.f,0.f}, bt[4] = {0.f,0.f,0.f,0.f};
  for (int k = 0; k < 256; ++k) {
    float gwv = gw[k*256 + co];
    float bwv = bw[k*256 + co];
    #pragma unroll
    for (int bb = 0; bb < 4; ++bb) {
      float cv = condl[(slot*4 + bb)*256 + k];
      g[bb]  = fmaf(cv, gwv, g[bb]);
      bt[bb] = fmaf(cv, bwv, bt[bb]);
    }
  }
  #pragma unroll
  for (int bb = 0; bb < 4; ++bb) {
    int b = slot*4 + bb;
    gammas[i*4096 + b*256 + co] = 1.0f + g[bb] + gbias[co];
    betas [i*4096 + b*256 + co] = bt[bb] + bbias[co];
  }
}

// ---------------- weight prepack: coalesced read + coalesced uint4 writes ----------------
// dst layout per conv: [cotile(4)][chunk(8)][tap][plane(2)][co64][ci32] halves
template<int TAPS>
__device__ __forceinline__ void wprep_body(const float* __restrict__ src,
                                           unsigned short* __restrict__ dst,
                                           int cotile, int chunk, int t) {
  int cow = t >> 2, ci8 = (t & 3) * 8;
  const float* s0 = src + ((size_t)(cotile*64 + cow)*256 + chunk*32 + ci8)*TAPS;
  float v[8*TAPS];
  #pragma unroll
  for (int i = 0; i < 8*TAPS; ++i) v[i] = s0[i];   // contiguous: wave covers dense runs
  unsigned short* dblk = dst + (size_t)cotile*(8*TAPS*4096) + (size_t)chunk*(TAPS*4096);
  #pragma unroll
  for (int tap = 0; tap < TAPS; ++tap) {
    unsigned hi2[4], lo2[4];
    #pragma unroll
    for (int jj = 0; jj < 4; ++jj) {
      float a = v[(jj*2+0)*TAPS + tap], b = v[(jj*2+1)*TAPS + tap];
      unsigned short ha = f2bf(a), hb = f2bf(b);
      unsigned short la = f2bf(a - __uint_as_float((unsigned)ha << 16));
      unsigned short lb = f2bf(b - __uint_as_float((unsigned)hb << 16));
      hi2[jj] = (unsigned)ha | ((unsigned)hb << 16);
      lo2[jj] = (unsigned)la | ((unsigned)lb << 16);
    }
    uint4 H; H.x = hi2[0]; H.y = hi2[1]; H.z = hi2[2]; H.w = hi2[3];
    uint4 L; L.x = lo2[0]; L.y = lo2[1]; L.z = lo2[2]; L.w = lo2[3];
    *(uint4*)(dblk + (size_t)(tap*2)*2048 + cow*32 + ci8) = H;
    *(uint4*)(dblk + (size_t)(tap*2+1)*2048 + cow*32 + ci8) = L;
  }
}

__global__ __launch_bounds__(256) void k_wprep(const float* __restrict__ conv_w,
                                               const float* __restrict__ tl_c1_w,
                                               unsigned short* __restrict__ wp) {
  int cc = blockIdx.x;
  int cotile = blockIdx.y >> 3, chunk = blockIdx.y & 7;
  if (cc == 30) wprep_body<1>(tl_c1_w, wp + (size_t)30*655360, cotile, chunk, threadIdx.x);
  else          wprep_body<5>(conv_w + (size_t)cc*327680, wp + (size_t)cc*655360, cotile, chunk, threadIdx.x);
}

// ---------------- embedding gather + stats atomics into slot 0 ----------------
__global__ void k_embed2(const int* __restrict__ inp, const float* __restrict__ emb,
                         float* __restrict__ x, float* __restrict__ stat0) {
  int bx = blockIdx.x;            // 160 blocks x 60 rows
  int c = threadIdx.x;
  int r0 = bx * 60;
  float s = 0.f, s2 = 0.f;
  for (int r = 0; r < 60; ++r) {
    int row = inp[r0 + r];
    float v = emb[(size_t)row*256 + c];
    x[(size_t)(r0 + r)*256 + c] = v;
    s += v; s2 = fmaf(v, v, s2);
  }
  atomicAdd(&stat0[c], s);
  atomicAdd(&stat0[256 + c], s2);
}

// ---------------- MFMA dilated conv: stats-reduce pre-phase, CCBN+ReLU fused staging,
// bf16x2 split, stats atomics in epilogue ----------------
// block = 64l x 64co, 4 waves of 32l x 32co. Z in LDS (pitch 40 halves).
// W read directly from prepacked global in exact B-fragment order.
// R4 lesson: out-of-range rows must stage EXACT ZERO (conv SAME padding).
template<int TAPS>
__global__ __launch_bounds__(256) void k_convm(const float* __restrict__ zin, float* __restrict__ out,
                        const float* __restrict__ stat_in, float* __restrict__ stat_out,
                        const float* __restrict__ gam, const float* __restrict__ bet,
                        const unsigned short* __restrict__ wpc,
                        const float* __restrict__ bias, int dil, int mode) {
  __shared__ unsigned short Zhi[80*40];
  __shared__ unsigned short Zlo[80*40];
  __shared__ float s_sc[256];
  __shared__ float s_sh[256];
  __shared__ float lsum[64];
  __shared__ float lsq[64];
  int t = threadIdx.x;
  int bx = blockIdx.x;
  int b  = bx / 10;
  int l0 = (bx % 10) * 64;
  int co0 = blockIdx.y * 64;
  int PAD = ((TAPS - 1)/2) * dil;
  int ROWS = 64 + 2*PAD;
  int w = t >> 6, lane = t & 63;
  int lsub = (w & 1) * 32, cosub = (w >> 1) * 32;
  int quad = lane >> 4, nlan = lane & 15;
  if (t < 64) { lsum[t] = 0.f; lsq[t] = 0.f; }
  // pre-phase: finalize BN stats for this stage, fold gamma/beta -> LDS scale/shift
  {
    float s = stat_in[t], s2 = stat_in[256 + t];
    float mu = s * (1.0f/9600.0f);
    float var = s2 * (1.0f/9600.0f) - mu*mu;
    float rs = rsqrtf(var + EPSv);
    float scale = rs * gam[b*256 + t];
    s_sc[t] = scale;
    s_sh[t] = fmaf(-mu, scale, bet[b*256 + t]);
  }

  floatx4 acc[2][2];
  #pragma unroll
  for (int i = 0; i < 2; ++i)
    #pragma unroll
    for (int j = 0; j < 2; ++j) acc[i][j] = (floatx4){0.f,0.f,0.f,0.f};

  const float* zb = zin + (size_t)b*600*256;
  int srow = t >> 3, fq = t & 7;
  int ar0 = (lsub + nlan) * 40 + quad * 8;
  int ar1 = (lsub + 16 + nlan) * 40 + quad * 8;

  for (int chunk = 0; chunk < 8; ++chunk) {
    int ci0 = chunk * 32;
    const unsigned short* pch = wpc + (size_t)(blockIdx.y*8 + chunk) * (TAPS*4096);
    short8 bh[TAPS][2], bl[TAPS][2];
    #pragma unroll
    for (int tap = 0; tap < TAPS; ++tap) {
      #pragma unroll
      for (int nt = 0; nt < 2; ++nt) {
        int cw = (cosub + nt*16 + nlan)*32 + quad*8;
        bh[tap][nt] = *(const short8*)(pch + (size_t)(tap*2)*2048 + cw);
        bl[tap][nt] = *(const short8*)(pch + (size_t)(tap*2+1)*2048 + cw);
      }
    }
    __syncthreads();   // prev chunk's A-reads done; also orders pre-phase LDS writes
    float4 sc4 = *(const float4*)&s_sc[ci0 + fq*4];
    float4 sh4 = *(const float4*)&s_sh[ci0 + fq*4];
    for (int r = srow; r < ROWS; r += 32) {
      int gl = l0 - PAD + r;
      bool inr = (gl >= 0 && gl < 600);
      float4 z = {0,0,0,0};
      if (inr) z = *(const float4*)&zb[(size_t)gl*256 + ci0 + fq*4];
      // SAME padding: rows outside [0,600) contribute exact zero
      float v0 = inr ? fmaxf(fmaf(z.x, sc4.x, sh4.x), 0.f) : 0.f;
      float v1 = inr ? fmaxf(fmaf(z.y, sc4.y, sh4.y), 0.f) : 0.f;
      float v2 = inr ? fmaxf(fmaf(z.z, sc4.z, sh4.z), 0.f) : 0.f;
      float v3 = inr ? fmaxf(fmaf(z.w, sc4.w, sh4.w), 0.f) : 0.f;
      unsigned short h0 = f2bf(v0), h1 = f2bf(v1), h2 = f2bf(v2), h3 = f2bf(v3);
      unsigned short e0 = f2bf(v0 - __uint_as_float((unsigned)h0 << 16));
      unsigned short e1 = f2bf(v1 - __uint_as_float((unsigned)h1 << 16));
      unsigned short e2 = f2bf(v2 - __uint_as_float((unsigned)h2 << 16));
      unsigned short e3 = f2bf(v3 - __uint_as_float((unsigned)h3 << 16));
      uint2 vh; vh.x = (unsigned)h0 | ((unsigned)h1 << 16);
      vh.y = (unsigned)h2 | ((unsigned)h3 << 16);
      uint2 vl; vl.x = (unsigned)e0 | ((unsigned)e1 << 16);
      vl.y = (unsigned)e2 | ((unsigned)e3 << 16);
      *(uint2*)&Zhi[r*40 + fq*4] = vh;
      *(uint2*)&Zlo[r*40 + fq*4] = vl;
    }
    __syncthreads();
    #pragma unroll
    for (int tap = 0; tap < TAPS; ++tap) {
      int sh = tap * dil * 40;
      short8 ah0 = *(const short8*)&Zhi[ar0 + sh];
      short8 ah1 = *(const short8*)&Zhi[ar1 + sh];
      short8 al0 = *(const short8*)&Zlo[ar0 + sh];
      short8 al1 = *(const short8*)&Zlo[ar1 + sh];
      #pragma unroll
      for (int nt = 0; nt < 2; ++nt) {
        acc[0][nt] = __builtin_amdgcn_mfma_f32_16x16x32_bf16(ah0, bh[tap][nt], acc[0][nt], 0, 0, 0);
        acc[0][nt] = __builtin_amdgcn_mfma_f32_16x16x32_bf16(ah0, bl[tap][nt], acc[0][nt], 0, 0, 0);
        acc[0][nt] = __builtin_amdgcn_mfma_f32_16x16x32_bf16(al0, bh[tap][nt], acc[0][nt], 0, 0, 0);
        acc[1][nt] = __builtin_amdgcn_mfma_f32_16x16x32_bf16(ah1, bh[tap][nt], acc[1][nt], 0, 0, 0);
        acc[1][nt] = __builtin_amdgcn_mfma_f32_16x16x32_bf16(ah1, bl[tap][nt], acc[1][nt], 0, 0, 0);
        acc[1][nt] = __builtin_amdgcn_mfma_f32_16x16x32_bf16(al1, bh[tap][nt], acc[1][nt], 0, 0, 0);
      }
    }
  }

  // epilogue: bias (+residual), store, stats partials -> global atomics
  float bsv[2], ssum[2] = {0.f, 0.f}, ssq[2] = {0.f, 0.f};
  #pragma unroll
  for (int nt = 0; nt < 2; ++nt) bsv[nt] = bias[co0 + cosub + nt*16 + nlan];
  #pragma unroll
  for (int mt = 0; mt < 2; ++mt) {
    #pragma unroll
    for (int r = 0; r < 4; ++r) {
      int l = l0 + lsub + mt*16 + quad*4 + r;
      if (l < 600) {
        size_t rowo = ((size_t)(b*600 + l))*256 + co0 + cosub;
        #pragma unroll
        for (int nt = 0; nt < 2; ++nt) {
          float v = acc[mt][nt][r] + bsv[nt];
          float* dst = &out[rowo + nt*16 + nlan];
          if (mode) v += *dst;
          *dst = v;
          ssum[nt] += v;
          ssq[nt] = fmaf(v, v, ssq[nt]);
        }
      }
    }
  }
  #pragma unroll
  for (int nt = 0; nt < 2; ++nt) {
    ssum[nt] += __shfl_xor(ssum[nt], 16, 64);
    ssum[nt] += __shfl_xor(ssum[nt], 32, 64);
    ssq[nt]  += __shfl_xor(ssq[nt], 16, 64);
    ssq[nt]  += __shfl_xor(ssq[nt], 32, 64);
  }
  if (quad == 0) {
    #pragma unroll
    for (int nt = 0; nt < 2; ++nt) {
      atomicAdd(&lsum[cosub + nt*16 + nlan], ssum[nt]);
      atomicAdd(&lsq [cosub + nt*16 + nlan], ssq[nt]);
    }
  }
  __syncthreads();
  if (t < 64) {
    atomicAdd(&stat_out[co0 + t], lsum[t]);
    atomicAdd(&stat_out[256 + co0 + t], lsq[t]);
  }
}

// ---------------- token-length final 256->1 conv + relu (CCBN stats fused inline) ----------------
__global__ void k_tl2(const float* __restrict__ z, const float* __restrict__ stat,
                      const float* __restrict__ gam, const float* __restrict__ bet,
                      const float* __restrict__ w2, const float* __restrict__ b2,
                      float* __restrict__ tl) {
  int t = threadIdx.x;
  int row = blockIdx.x * 4 + (t >> 6);
  int lane = t & 63;
  int b = row / 600;
  float4 s1 = *(const float4*)&stat[lane*4];
  float4 s2 = *(const float4*)&stat[256 + lane*4];
  float4 gm = *(const float4*)&gam[b*256 + lane*4];
  float4 bt = *(const float4*)&bet[b*256 + lane*4];
  float sc[4], sh[4];
  {
    float sv[4] = {s1.x, s1.y, s1.z, s1.w};
    float qv[4] = {s2.x, s2.y, s2.z, s2.w};
    float gv[4] = {gm.x, gm.y, gm.z, gm.w};
    float bv[4] = {bt.x, bt.y, bt.z, bt.w};
    #pragma unroll
    for (int i = 0; i < 4; ++i) {
      float mu = sv[i] * (1.0f/9600.0f);
      float var = qv[i] * (1.0f/9600.0f) - mu*mu;
      float rs = rsqrtf(var + EPSv);
      sc[i] = rs * gv[i];
      sh[i] = fmaf(-mu, sc[i], bv[i]);
    }
  }
  float4 zr = *(const float4*)&z[(size_t)row*256 + lane*4];
  float4 wr = *(const float4*)&w2[lane*4];
  float z0 = fmaxf(fmaf(zr.x, sc[0], sh[0]), 0.f);
  float z1 = fmaxf(fmaf(zr.y, sc[1], sh[1]), 0.f);
  float z2 = fmaxf(fmaf(zr.z, sc[2], sh[2]), 0.f);
  float z3 = fmaxf(fmaf(zr.w, sc[3], sh[3]), 0.f);
  float s = z0*wr.x + z1*wr.y + z2*wr.z + z3*wr.w;
  for (int m = 32; m >= 1; m >>= 1) s += __shfl_xor(s, m, 64);
  if (lane == 0) tl[row] = fmaxf(s + b2[0], 0.f);
}

// ---------------- per-batch cumsum -> ends (output 1) + centers ----------------
__global__ void k_cumsum(const float* __restrict__ tl, float* __restrict__ centers,
                         float* __restrict__ out_len) {
  int b = blockIdx.x; int lane = threadIdx.x;
  float carry = 0.f;
  for (int ch = 0; ch < 10; ++ch) {
    int l = ch*64 + lane;
    float v = (l < 600) ? tl[b*600 + l] : 0.f;
    float s = v;
    #pragma unroll
    for (int off = 1; off < 64; off <<= 1) {
      float n = __shfl_up(s, off, 64);
      if (lane >= off) s += n;
    }
    float ends = carry + s;
    if (l < 600) {
      centers[b*600 + l] = ends - 0.5f*v;
      out_len[b*600 + l] = ends;
    }
    carry = __shfl(ends, 63, 64);
  }
}

// ---------------- fp32 (b,l,c) -> bf16 (b,c,l) transpose, l padded to 640 ----------------
__global__ void k_tobf16(const float* __restrict__ x, unsigned short* __restrict__ fbT) {
  __shared__ unsigned short T[64*66];
  int b = blockIdx.x, lt = blockIdx.y, ct = blockIdx.z;
  int t = threadIdx.x;
  int i4 = t >> 6;
  int j = t & 63;
  #pragma unroll
  for (int r = 0; r < 16; ++r) {
    int li = i4*16 + r;
    int l = lt*64 + li;
    float v = (l < 600) ? x[((size_t)(b*600 + l))*256 + ct*64 + j] : 0.f;
    T[j*66 + li] = f2bf(v);
  }
  __syncthreads();
  int row = t >> 2, seg = (t & 3) * 16;
  unsigned vv[8];
  #pragma unroll
  for (int k = 0; k < 8; ++k)
    vv[k] = *(const unsigned*)&T[row*66 + seg + k*2];
  size_t dsth = ((size_t)(b*256 + ct*64 + row))*640 + lt*64 + seg;
  unsigned* du = (unsigned*)fbT;
  uint4 a; a.x = vv[0]; a.y = vv[1]; a.z = vv[2]; a.w = vv[3];
  uint4 c4; c4.x = vv[4]; c4.y = vv[5]; c4.z = vv[6]; c4.w = vv[7];
  *(uint4*)(du + dsth/2) = a;
  *(uint4*)(du + dsth/2 + 4) = c4;
}

// ---------------- alignment einsum via bf16 MFMA ----------------
__global__ __launch_bounds__(256) void k_align2(const unsigned short* __restrict__ fbT,
                        const float* __restrict__ centers, float* __restrict__ outp) {
  __shared__ float cen[600];
  __shared__ float mrow[64];
  __shared__ float isum[64];
  __shared__ unsigned short Wt[64*72];
  __shared__ unsigned short Ft[256*72];
  int b = blockIdx.x;
  int o0 = blockIdx.y * 64;
  int t = threadIdx.x;
  int wv = t >> 6, lane = t & 63;
  for (int i = t; i < 600; i += 256) cen[i] = centers[b*600 + i];
  __syncthreads();
  for (int rr = 0; rr < 16; ++rr) {
    int oi = wv*16 + rr;
    float opos = (float)(o0 + oi);
    float mx = -3.0e38f;
    for (int l = lane; l < 600; l += 64) {
      float d = cen[l] - opos;
      mx = fmaxf(mx, -d*d*0.1f);
    }
    #pragma unroll
    for (int mm = 32; mm >= 1; mm >>= 1) mx = fmaxf(mx, __shfl_xor(mx, mm, 64));
    float sum = 0.f;
    for (int l = lane; l < 600; l += 64) {
      float d = cen[l] - opos;
      sum += __expf(-d*d*0.1f - mx);
    }
    #pragma unroll
    for (int mm = 32; mm >= 1; mm >>= 1) sum += __shfl_xor(sum, mm, 64);
    if (lane == 0) { mrow[oi] = mx; isum[oi] = 1.0f / sum; }
  }
  __syncthreads();
  floatx4 acc[4][4];
  #pragma unroll
  for (int i = 0; i < 4; ++i)
    #pragma unroll
    for (int j = 0; j < 4; ++j)
      acc[i][j] = (floatx4){0.f, 0.f, 0.f, 0.f};
  int quad = lane >> 4;
  int nlan = lane & 15;
  int oi_w = t >> 2;
  int lq = (t & 3) * 16;
  float mo = mrow[oi_w];
  float opos_w = (float)(o0 + oi_w);
  const unsigned short* srcb = fbT + ((size_t)b*256)*640;

  for (int ch = 0; ch < 10; ++ch) {
    int lc0 = ch * 64;
    __syncthreads();
    #pragma unroll
    for (int jj = 0; jj < 16; jj += 2) {
      int l0i = lc0 + lq + jj;
      float e0 = 0.f, e1 = 0.f;
      if (l0i < 600)     { float d = cen[l0i] - opos_w;     e0 = __expf(-d*d*0.1f - mo); }
      if (l0i + 1 < 600) { float d = cen[l0i + 1] - opos_w; e1 = __expf(-d*d*0.1f - mo); }
      unsigned pk = (unsigned)f2bf(e0) | ((unsigned)f2bf(e1) << 16);
      *(unsigned*)&Wt[oi_w*72 + lq + jj] = pk;
    }
    #pragma unroll
    for (int it = 0; it < 8; ++it) {
      int idx = t + it*256;
      int c = idx >> 3, part = idx & 7;
      uint4 v = *(const uint4*)(srcb + (size_t)c*640 + lc0 + part*8);
      *(uint4*)&Ft[c*72 + part*8] = v;
    }
    __syncthreads();
    #pragma unroll
    for (int ks = 0; ks < 2; ++ks) {
      int ko = ks*32 + quad*8;
      short8 af[4], bfr[4];
      #pragma unroll
      for (int mt = 0; mt < 4; ++mt)
        af[mt] = *(const short8*)&Wt[(mt*16 + nlan)*72 + ko];
      #pragma unroll
      for (int nt = 0; nt < 4; ++nt)
        bfr[nt] = *(const short8*)&Ft[(wv*64 + nt*16 + nlan)*72 + ko];
      #pragma unroll
      for (int mt = 0; mt < 4; ++mt)
        #pragma unroll
        for (int nt = 0; nt < 4; ++nt)
          acc[mt][nt] = __builtin_amdgcn_mfma_f32_16x16x32_bf16(af[mt], bfr[nt], acc[mt][nt], 0, 0, 0);
    }
  }
  #pragma unroll
  for (int mt = 0; mt < 4; ++mt) {
    #pragma unroll
    for (int r = 0; r < 4; ++r) {
      int oi = mt*16 + quad*4 + r;
      int o = o0 + oi;
      if (o < 6000) {
        float sc = isum[oi];
        #pragma unroll
        for (int nt = 0; nt < 4; ++nt) {
          int c = wv*64 + nt*16 + nlan;
          outp[((size_t)b*6000 + o)*256 + c] = acc[mt][nt][r] * sc;
        }
      }
    }
  }
}

extern "C" void kernel_launch(void* const* d_in, const int* in_sizes, int n_in,
                              void* d_out, int out_size, void* d_ws, size_t ws_size,
                              hipStream_t stream) {
  const int*   inputs = (const int*)  d_in[0];
  const float* spk    = (const float*)d_in[1];
  const float* noise  = (const float*)d_in[2];
  const float* emb    = (const float*)d_in[3];
  const float* conv_w = (const float*)d_in[4];
  const float* conv_b = (const float*)d_in[5];
  const float* g_w    = (const float*)d_in[6];
  const float* g_b    = (const float*)d_in[7];
  const float* b_w    = (const float*)d_in[8];
  const float* b_b    = (const float*)d_in[9];
  const float* tl_g_w = (const float*)d_in[10];
  const float* tl_g_b = (const float*)d_in[11];
  const float* tl_b_w = (const float*)d_in[12];
  const float* tl_b_b = (const float*)d_in[13];
  const float* tl_c1_w = (const float*)d_in[14];
  const float* tl_c1_b = (const float*)d_in[15];
  const float* tl_c2_w = (const float*)d_in[16];
  const float* tl_c2_b = (const float*)d_in[17];
  float* out = (float*)d_out;

  float* ws = (float*)d_ws;
  float* x       = ws;                 // 2457600
  float* A       = x + 2457600;        // 2457600
  float* Bf      = A + 2457600;        // 2457600 (reused as fbT at the end)
  float* gammas  = Bf + 2457600;       // 131072
  float* betas   = gammas + 131072;    // 131072
  float* statacc = betas + 131072;     // 32 slots x 512 = 16384
  float* tl      = statacc + 16384;    // 9600
  float* cen     = tl + 9600;          // 9600
  unsigned short* wp = (unsigned short*)(cen + 9600);   // ~39.6 MB
  unsigned short* fbT = (unsigned short*)Bf;

  k_zero<<<dim3(64), dim3(256), 0, stream>>>(statacc);
  k_wprep<<<dim3(31, 32), dim3(256), 0, stream>>>(conv_w, tl_c1_w, wp);
  k_gamma_beta<<<dim3(32, 4), dim3(256), 0, stream>>>(spk, noise, g_w, g_b, b_w, b_b,
      tl_g_w, tl_g_b, tl_b_w, tl_b_b, gammas, betas);
  k_embed2<<<dim3(160), dim3(256), 0, stream>>>(inputs, emb, x, statacc);

  const int dils[3] = {1, 2, 4};
  for (int blk = 0; blk < 10; ++blk) {
    const float* srcs[3] = {x, A, Bf};
    float*       dsts[3] = {A, Bf, x};   // ping-pong; never in-place (R2 race)
    for (int j = 0; j < 3; ++j) {
      int idx = blk*3 + j;
      int mode = (j == 2) ? 1 : 0;
      k_convm<5><<<dim3(160, 4), dim3(256), 0, stream>>>(srcs[j], dsts[j],
          statacc + idx*512, statacc + (idx+1)*512,
          gammas + idx*4096, betas + idx*4096,
          wp + (size_t)idx*655360, conv_b + idx*256, dils[j], mode);
    }
  }
  // token-length head
  k_convm<1><<<dim3(160, 4), dim3(256), 0, stream>>>(x, A,
      statacc + 30*512, statacc + 31*512,
      gammas + 30*4096, betas + 30*4096,
      wp + (size_t)30*655360, tl_c1_b, 1, 0);
  k_tl2<<<dim3(2400), dim3(256), 0, stream>>>(A, statacc + 31*512,
      gammas + 31*4096, betas + 31*4096, tl_c2_w, tl_c2_b, tl);
  k_cumsum<<<dim3(16), dim3(64), 0, stream>>>(tl, cen, out + 24576000);
  // alignment einsum (bf16 MFMA)
  k_tobf16<<<dim3(16, 10, 4), dim3(256), 0, stream>>>(x, fbT);
  k_align2<<<dim3(16, 94), dim3(256), 0, stream>>>(fbT, cen, out);
}